// Round 1
// 5055.692 us; speedup vs baseline: 1.3372x; 1.3372x over previous
//
#include <hip/hip_runtime.h>
#include <stdint.h>

#define GM 4096
#define GK 2048
#define GN 5632
#define GE 8
#define GTOPK 2

typedef __attribute__((ext_vector_type(4))) float f32x4;
typedef __attribute__((ext_vector_type(8))) short short8;
typedef __attribute__((ext_vector_type(4))) uint32_t u32x4;

__device__ __forceinline__ void gld16(const void* g, void* l) {
  __builtin_amdgcn_global_load_lds((const __attribute__((address_space(1))) void*)g,
                                   (__attribute__((address_space(3))) void*)l, 16, 0, 0);
}

// pack hi16(hi),hi16(lo) -> one u32 holding two bf16 (truncation) -- fallback path only
__device__ __forceinline__ uint32_t pack2(float hi, float lo) {
  return __builtin_amdgcn_perm(__float_as_uint(hi), __float_as_uint(lo), 0x07060302u);
}

__device__ __forceinline__ unsigned short bf16rne(float f) {
  uint32_t u = __float_as_uint(f);
  u += 0x7FFFu + ((u >> 16) & 1u);
  return (unsigned short)(u >> 16);
}

// ---------------- routing ----------------
__global__ void route_count(const int* __restrict__ ids, int* __restrict__ counts) {
  int i = blockIdx.x * blockDim.x + threadIdx.x;
  if (i < GM * GTOPK) atomicAdd(&counts[ids[i]], 1);
}

__global__ void route_scan(const int* __restrict__ counts, int* __restrict__ offs) {
  if (threadIdx.x == 0) {
    int s = 0;
    for (int e = 0; e < GE; ++e) { offs[e] = s; s += counts[e]; }
    offs[GE] = s;
  }
}

__global__ void route_scatter(const int* __restrict__ ids, const float* __restrict__ wts,
                              const int* __restrict__ offs, int* __restrict__ fill,
                              int* __restrict__ slot_token, float* __restrict__ slot_gate,
                              int* __restrict__ inv_slot) {
  int i = blockIdx.x * blockDim.x + threadIdx.x;
  if (i < GM * GTOPK) {
    int e = ids[i];
    int pos = offs[e] + atomicAdd(&fill[e], 1);
    slot_token[pos] = i / GTOPK;
    slot_gate[pos] = wts[i];
    inv_slot[i] = pos;  // token t's TOPK slots: inv_slot[2t], inv_slot[2t+1]
  }
}

// ---------------- fp32 -> bf16 (rne), 8 elems/thread ----------------
__global__ void cvt_bf16(const float* __restrict__ x, unsigned short* __restrict__ y, int n8) {
  int i = blockIdx.x * blockDim.x + threadIdx.x;
  if (i >= n8) return;
  const f32x4* xp = (const f32x4*)x;
  f32x4 a = xp[2 * i], b = xp[2 * i + 1];
  u32x4 o;
  o.x = ((uint32_t)bf16rne(a.y) << 16) | bf16rne(a.x);
  o.y = ((uint32_t)bf16rne(a.w) << 16) | bf16rne(a.z);
  o.z = ((uint32_t)bf16rne(b.y) << 16) | bf16rne(b.x);
  o.w = ((uint32_t)bf16rne(b.w) << 16) | bf16rne(b.z);
  ((u32x4*)y)[i] = o;
}

// ---------------- fused grouped GEMM, bf16 A and B (fast path) ----------------
// m97 structure: 128x128 tile (MODE1: 128 M x 64 out cols via 128 B rows gate+up),
// BK=64, 4 waves (2x2), 32 MFMA/wave per barrier pair, global_load_lds width 16.
// LDS fragment-permuted: unit u (subtile s=u>>1, khalf kk=u&1) at u*1024;
// every ds_read_b128 and every gld16 dest is base + lane*16 (0 bank conflicts).
// Lane mapping per 16x16x32 fragment: row/col = lane&15, k = (lane>>4)*8 .. +8.
template <int MODE>
__global__ __launch_bounds__(256, 2)
void moe_gemm_bf16(const unsigned short* __restrict__ A,
                   const unsigned short* __restrict__ Bw,
                   const int* __restrict__ offs,
                   const int* __restrict__ slot_token,
                   const float* __restrict__ slot_gate,
                   unsigned short* __restrict__ act,
                   float* __restrict__ scratch)
{
  constexpr int KR = (MODE == 1) ? GK : GN;  // reduction length (row length of A and B)
  const int e = blockIdx.z;
  const int segs = offs[e];
  const int segc = offs[e + 1] - segs;
  const int mtile = blockIdx.x;
  if (mtile * 128 >= segc) return;           // dynamic segment: spare x-blocks early-exit
  const int ntile = blockIdx.y;
  const int tid = threadIdx.x;
  const int w = tid >> 6, lane = tid & 63;
  const int wm = w >> 1, wn = w & 1;

  __shared__ __align__(16) char lds[32 * 1024];  // A 16KB + B 16KB, both bf16

  const unsigned short* Be = Bw + (size_t)e * (size_t)((MODE == 1) ? (2 * GN * GK) : (GK * GN));

  // staging source pointers: 4 A units + 4 B units per thread (16B bf16x8 each)
  const unsigned short* asrc[4];
  const unsigned short* bsrc[4];
  {
    const int r16 = lane & 15;
    const int koff = (lane >> 4) * 8;
    #pragma unroll
    for (int c = 0; c < 4; ++c) {
      int u = c * 4 + w;                     // wave-unit 0..15
      int s = u >> 1, kk = u & 1;            // subtile (16 rows), k-half (32 elems)
      int slot = segs + mtile * 128 + s * 16 + r16;
      if (slot >= segs + segc) slot = segs;  // clamp: safe row, masked in epilogue
      size_t arow = (MODE == 1) ? (size_t)slot_token[slot] : (size_t)slot;
      asrc[c] = A + arow * KR + (kk * 32 + koff);
      int brow;
      if (MODE == 1)  // subtiles 0-3 gate rows, 4-7 up rows (same out cols -> in-reg silu)
        brow = (s < 4) ? (ntile * 64 + s * 16 + r16) : (GN + ntile * 64 + (s - 4) * 16 + r16);
      else
        brow = ntile * 128 + s * 16 + r16;
      bsrc[c] = Be + (size_t)brow * KR + (kk * 32 + koff);
    }
  }
  char* adst[4];
  char* bdst[4];
  #pragma unroll
  for (int c = 0; c < 4; ++c) {
    adst[c] = lds + (c * 4 + w) * 1024;            // u*1024 == s*2048 + kk*1024
    bdst[c] = lds + 16384 + (c * 4 + w) * 1024;
  }

  const f32x4 zero4 = {0.f, 0.f, 0.f, 0.f};
  f32x4 acc[4][4];
  #pragma unroll
  for (int a_ = 0; a_ < 4; ++a_)
    #pragma unroll
    for (int b_ = 0; b_ < 4; ++b_) acc[a_][b_] = zero4;

  const char* ldsA = lds + (wm * 4) * 2048 + lane * 16;

  for (int k0 = 0; k0 < KR; k0 += 64) {
    #pragma unroll
    for (int c = 0; c < 4; ++c) gld16(asrc[c] + k0, adst[c]);
    #pragma unroll
    for (int c = 0; c < 4; ++c) gld16(bsrc[c] + k0, bdst[c]);
    __syncthreads();  // compiler emits vmcnt(0) drain before s_barrier

    #pragma unroll
    for (int kk = 0; kk < 2; ++kk) {
      short8 afr[4];
      #pragma unroll
      for (int mt = 0; mt < 4; ++mt)
        afr[mt] = *(const short8*)(ldsA + mt * 2048 + kk * 1024);
      #pragma unroll
      for (int j = 0; j < 4; ++j) {
        int sB = (MODE == 1) ? ((j < 2) ? (wn * 2 + j) : (4 + wn * 2 + (j - 2))) : (wn * 4 + j);
        short8 bfr = *(const short8*)(lds + 16384 + sB * 2048 + kk * 1024 + lane * 16);
        #pragma unroll
        for (int mt = 0; mt < 4; ++mt)
          acc[mt][j] = __builtin_amdgcn_mfma_f32_16x16x32_bf16(afr[mt], bfr, acc[mt][j], 0, 0, 0);
      }
    }
    __syncthreads();
  }

  // ---- epilogue: C/D mapping col=lane&15, row=(lane>>4)*4+r ----
  int lcol = lane & 15;
  int rbase = (lane >> 4) * 4;
  if (MODE == 1) {
    #pragma unroll
    for (int mt = 0; mt < 4; ++mt) {
      int mloc = mtile * 128 + wm * 64 + mt * 16 + rbase;
      #pragma unroll
      for (int j = 0; j < 2; ++j) {
        int col = ntile * 64 + wn * 32 + j * 16 + lcol;
        f32x4 g = acc[mt][j], u = acc[mt][2 + j];  // identical lane mapping -> in-reg silu
        #pragma unroll
        for (int r = 0; r < 4; ++r) {
          int ml = mloc + r;
          if (ml < segc) {
            float gv = g[r];
            float s = gv / (1.f + __expf(-gv));
            act[(size_t)(segs + ml) * GN + col] = bf16rne(s * u[r]);
          }
        }
      }
    }
  } else {
    // no atomics: per-slot scratch, merged later via inv_slot
    #pragma unroll
    for (int mt = 0; mt < 4; ++mt) {
      int mloc = mtile * 128 + wm * 64 + mt * 16 + rbase;
      #pragma unroll
      for (int r = 0; r < 4; ++r) {
        int ml = mloc + r;
        if (ml < segc) {
          int slot = segs + ml;
          float gate = slot_gate[slot];
          float* srow = scratch + (size_t)slot * GK;
          #pragma unroll
          for (int j = 0; j < 4; ++j) {
            int col = ntile * 128 + wn * 64 + j * 16 + lcol;
            srow[col] = gate * acc[mt][j][r];
          }
        }
      }
    }
  }
}

// out[t,:] = scratch[slot(t,0),:] + scratch[slot(t,1),:]   (gates pre-applied)
__global__ void merge_out(const float* __restrict__ scratch, const int* __restrict__ inv,
                          float* __restrict__ out) {
  int i = blockIdx.x * blockDim.x + threadIdx.x;
  if (i >= GM * (GK / 8)) return;
  int token = i >> 8;              // GK/8 == 256
  int c = (i & 255) * 8;
  const float* s0 = scratch + (size_t)inv[2 * token] * GK + c;
  const float* s1 = scratch + (size_t)inv[2 * token + 1] * GK + c;
  f32x4 a0 = ((const f32x4*)s0)[0], a1 = ((const f32x4*)s0)[1];
  f32x4 b0 = ((const f32x4*)s1)[0], b1 = ((const f32x4*)s1)[1];
  float* o = out + (size_t)token * GK + c;
  ((f32x4*)o)[0] = a0 + b0;
  ((f32x4*)o)[1] = a1 + b1;
}

// ---------------- fallback (fp32 B in LDS, BK=32) — verbatim previous kernel ----------------
template <int MODE>
__global__ __launch_bounds__(256, 2)
void moe_gemm_f32(const unsigned short* __restrict__ A,
                  const float* __restrict__ B,
                  const int* __restrict__ offs,
                  const int* __restrict__ slot_token,
                  const float* __restrict__ slot_gate,
                  unsigned short* __restrict__ act,
                  float* __restrict__ out)
{
  constexpr int KR = (MODE == 1) ? GK : GN;
  const int e = blockIdx.z;
  const int segs = offs[e];
  const int segc = offs[e + 1] - segs;
  const int mtile = blockIdx.x;
  if (mtile * 128 >= segc) return;
  const int ntile = blockIdx.y;
  const int tid = threadIdx.x;
  const int w = tid >> 6, lane = tid & 63;
  const int wm = w >> 1, wn = w & 1;

  __shared__ __align__(16) char lds[24 * 1024];

  const float* Be = B + (size_t)e * (size_t)((MODE == 1) ? (2 * GN * GK) : (GK * GN));

  const char* aptr[2];
  {
    int m16 = lane & 15, h = lane >> 4;
    #pragma unroll
    for (int c = 0; c < 2; ++c) {
      int s = c * 4 + w;
      int slot = segs + mtile * 128 + s * 16 + m16;
      if (slot >= segs + segc) slot = segs;
      size_t arow = (MODE == 1) ? (size_t)slot_token[slot] : (size_t)slot;
      aptr[c] = (const char*)(A + arow * KR + h * 8);
    }
  }
  const char* bptr[4];
  {
    int n16 = lane & 15, k4hi = lane >> 4;
    #pragma unroll
    for (int c = 0; c < 4; ++c) {
      int q = c * 4 + w;
      int s = q >> 1, hh = q & 1;
      int k4 = hh * 4 + k4hi;
      int brow;
      if (MODE == 1)
        brow = (s < 4) ? (ntile * 64 + s * 16 + n16) : (GN + ntile * 64 + (s - 4) * 16 + n16);
      else
        brow = ntile * 128 + s * 16 + n16;
      bptr[c] = (const char*)(Be + (size_t)brow * KR + k4 * 4);
    }
  }
  char* ldsAdst0 = lds + w * 1024;
  char* ldsAdst1 = lds + (4 + w) * 1024;
  char* ldsBdst[4];
  #pragma unroll
  for (int c = 0; c < 4; ++c) ldsBdst[c] = lds + 8192 + (c * 4 + w) * 1024;

  const f32x4 zero4 = {0.f, 0.f, 0.f, 0.f};
  f32x4 acc[4][4];
  #pragma unroll
  for (int a_ = 0; a_ < 4; ++a_)
    #pragma unroll
    for (int b_ = 0; b_ < 4; ++b_) acc[a_][b_] = zero4;

  const char* ldsAfr = lds + (wm * 4) * 1024 + lane * 16;

  for (int k0 = 0; k0 < KR; k0 += 32) {
    gld16(aptr[0] + (size_t)k0 * 2, ldsAdst0);
    gld16(aptr[1] + (size_t)k0 * 2, ldsAdst1);
    #pragma unroll
    for (int c = 0; c < 4; ++c) gld16(bptr[c] + (size_t)k0 * 4, ldsBdst[c]);
    __syncthreads();

    short8 afr[4];
    #pragma unroll
    for (int mt = 0; mt < 4; ++mt) afr[mt] = *(const short8*)(ldsAfr + mt * 1024);
    #pragma unroll
    for (int j = 0; j < 4; ++j) {
      int sB = (MODE == 1) ? ((j < 2) ? (wn * 2 + j) : (4 + wn * 2 + j - 2)) : (wn * 4 + j);
      const char* lb = lds + 8192 + sB * 2048 + ((lane >> 4) * 32 + (lane & 15)) * 16;
      f32x4 b0 = *(const f32x4*)lb;
      f32x4 b1 = *(const f32x4*)(lb + 256);
      union { uint32_t u[4]; short8 s8; } bu;
      bu.u[0] = pack2(b0.y, b0.x);
      bu.u[1] = pack2(b0.w, b0.z);
      bu.u[2] = pack2(b1.y, b1.x);
      bu.u[3] = pack2(b1.w, b1.z);
      #pragma unroll
      for (int mt = 0; mt < 4; ++mt)
        acc[mt][j] = __builtin_amdgcn_mfma_f32_16x16x32_bf16(afr[mt], bu.s8, acc[mt][j], 0, 0, 0);
    }
    __syncthreads();
  }

  int lcol = lane & 15;
  int rbase = (lane >> 4) * 4;
  if (MODE == 1) {
    #pragma unroll
    for (int mt = 0; mt < 4; ++mt) {
      int mloc = mtile * 128 + wm * 64 + mt * 16 + rbase;
      #pragma unroll
      for (int j = 0; j < 2; ++j) {
        int col = ntile * 64 + wn * 32 + j * 16 + lcol;
        f32x4 g = acc[mt][j], u = acc[mt][2 + j];
        #pragma unroll
        for (int r = 0; r < 4; ++r) {
          int ml = mloc + r;
          if (ml < segc) {
            float gv = g[r];
            float s = gv / (1.f + __expf(-gv));
            act[(size_t)(segs + ml) * GN + col] = bf16rne(s * u[r]);
          }
        }
      }
    }
  } else {
    #pragma unroll
    for (int mt = 0; mt < 4; ++mt) {
      int mloc = mtile * 128 + wm * 64 + mt * 16 + rbase;
      #pragma unroll
      for (int r = 0; r < 4; ++r) {
        int ml = mloc + r;
        if (ml < segc) {
          int slot = segs + ml;
          float gate = slot_gate[slot];
          float* orow = out + (size_t)slot_token[slot] * GK;
          #pragma unroll
          for (int j = 0; j < 4; ++j) {
            int col = ntile * 128 + wn * 64 + j * 16 + lcol;
            atomicAdd(&orow[col], gate * acc[mt][j][r]);
          }
        }
      }
    }
  }
}

extern "C" void kernel_launch(void* const* d_in, const int* in_sizes, int n_in,
                              void* d_out, int out_size, void* d_ws, size_t ws_size,
                              hipStream_t stream) {
  const float* hs  = (const float*)d_in[0];
  const float* w1  = (const float*)d_in[1];
  const float* w2  = (const float*)d_in[2];
  const float* tkw = (const float*)d_in[3];
  const int*   tki = (const int*)d_in[4];
  float* out = (float*)d_out;

  char* ws = (char*)d_ws;
  int*   counts     = (int*)(ws + 0);
  int*   fill       = (int*)(ws + 64);
  int*   offs       = (int*)(ws + 128);
  int*   slot_token = (int*)(ws + 1024);
  float* slot_gate  = (float*)(ws + 1024 + 32768);
  int*   inv_slot   = (int*)(ws + 66560);
  unsigned short* hsb = (unsigned short*)(ws + 131072);
  unsigned short* act = (unsigned short*)(ws + 131072 + (size_t)GM * GK * 2);

  // fast-path extra workspace: bf16 weights + fp32 per-slot scratch
  const size_t off_w1b = 131072 + (size_t)GM * GK * 2 + (size_t)GM * GTOPK * GN * 2;  // 109.2MB
  const size_t sz_w1b  = (size_t)GE * 2 * GN * GK * 2;   // 369.1MB
  const size_t off_w2b = off_w1b + sz_w1b;
  const size_t sz_w2b  = (size_t)GE * GK * GN * 2;       // 184.5MB
  const size_t off_scr = off_w2b + sz_w2b;
  const size_t sz_scr  = (size_t)GM * GTOPK * GK * 4;    // 67.1MB
  const size_t need    = off_scr + sz_scr;               // ~730MB

  hipMemsetAsync(ws, 0, 1024, stream);

  route_count<<<(GM * GTOPK + 255) / 256, 256, 0, stream>>>(tki, counts);
  route_scan<<<1, 64, 0, stream>>>(counts, offs);
  route_scatter<<<(GM * GTOPK + 255) / 256, 256, 0, stream>>>(tki, tkw, offs, fill,
                                                              slot_token, slot_gate, inv_slot);
  cvt_bf16<<<(GM * GK / 8 + 255) / 256, 256, 0, stream>>>(hs, hsb, GM * GK / 8);

  if (ws_size >= need) {
    unsigned short* w1b = (unsigned short*)(ws + off_w1b);
    unsigned short* w2b = (unsigned short*)(ws + off_w2b);
    float* scratch = (float*)(ws + off_scr);
    const int n8w1 = GE * 2 * GN * GK / 8;  // 23.07M threads
    const int n8w2 = GE * GK * GN / 8;      // 11.53M threads
    cvt_bf16<<<(n8w1 + 255) / 256, 256, 0, stream>>>(w1, w1b, n8w1);
    cvt_bf16<<<(n8w2 + 255) / 256, 256, 0, stream>>>(w2, w2b, n8w2);

    // x = m-tiles (fastest) so co-resident blocks share the same B slab -> L2 reuse
    moe_gemm_bf16<1><<<dim3(64, GN / 64, GE), 256, 0, stream>>>(hsb, w1b, offs, slot_token,
                                                                slot_gate, act, nullptr);
    moe_gemm_bf16<2><<<dim3(64, GK / 128, GE), 256, 0, stream>>>(act, w2b, offs, slot_token,
                                                                 slot_gate, nullptr, scratch);
    merge_out<<<(GM * (GK / 8) + 255) / 256, 256, 0, stream>>>(scratch, inv_slot, out);
  } else {
    // fallback: previous verified kernel (fp32 B staging + atomics)
    hipMemsetAsync(d_out, 0, (size_t)out_size * sizeof(float), stream);
    moe_gemm_f32<1><<<dim3(64, GN / 64, GE), 256, 0, stream>>>(hsb, w1, offs, slot_token,
                                                               slot_gate, act, nullptr);
    moe_gemm_f32<2><<<dim3(64, GK / 128, GE), 256, 0, stream>>>(act, w2, offs, slot_token,
                                                                slot_gate, nullptr, out);
  }
}